// Round 4
// baseline (489.070 us; speedup 1.0000x reference)
//
#include <hip/hip_runtime.h>

#define TLEN  4096
#define NROWS 4096
#define RPB   32            // rows per wave (= per block)
#define K     32            // timesteps staged per flush
#define NC    (TLEN / K)
#define LDPAD 66            // dwords per staged row: 64 data + 2 pad (bank-spread)
#define UN    8             // exact-path unroll

__device__ __forceinline__ float fexp2(float x) { return __builtin_amdgcn_exp2f(x); }
__device__ __forceinline__ float frcp(float x)  { return __builtin_amdgcn_rcpf(x); }
__device__ __forceinline__ float sigz(float z)  { return frcp(1.0f + fexp2(z)); }

// Swap adjacent lanes (lane ^ 1): DPP quad_perm [1,0,3,2].
__device__ __forceinline__ float lane_swap1(float v) {
    int r = __builtin_amdgcn_update_dpp(0, __float_as_int(v), 0xB1, 0xF, 0xF, true);
    return __int_as_float(r);
}

// ---------------------------------------------------------------------------
// Fast path: transcendental-free carried chain + LDS-staged coalesced stores.
// Lane pair (2r, 2r+1) owns row r: even lane = x-chain, odd = y-chain.
// Tracks e = 2^(c1*(s - mean_self)), p = 1 + e; partner's p via DPP.
// sigma_self = po*r, sigma_partner = p*r, r ~= 1/(p*po) (1 Newton step/iter).
// ---------------------------------------------------------------------------
__device__ void run_fast(const float* __restrict__ inp, const float* __restrict__ prm,
                         float* __restrict__ out, float* __restrict__ st) {
    const int lane = threadIdx.x;
    const int R0   = blockIdx.x * RPB;
    const int r_   = lane >> 1;
    const int par  = lane & 1;
    const int row  = R0 + r_;

    const float L2E = 1.4426950408889634f;
    const int inB = par ? 6 : 2, sfB = par ? 22 : 18, t2B = par ? 10 : 14;
    const float ic  = 1.0f / prm[par];
    const float g1  = prm[sfB] * ic, P1 = g1 * prm[sfB + 3], Gn1 = -g1; // self dir
    const float g2  = prm[t2B] * ic, P2 = g2 * prm[t2B + 3], Gn2 = -g2; // cross dir
    const float gA  = prm[inB] * ic, PA = gA * prm[inB + 3], GnA = -gA; // input dir
    const float c1i = -prm[inB + 2] * L2E, c0i = prm[inB + 2] * prm[inB + 1] * L2E;
    const float c1  = -prm[sfB + 2] * L2E;
    const float mean_s = prm[sfB + 1];
    const float T1 = 0.6931471805599453f;   // ln2
    const float T2 = 0.2402265069591007f;   // ln2^2/2  (deg-2: |w|<=0.02 guarded)

    float x = par ? 1.0f : 0.0f;
    float e = fexp2(c1 * (x - mean_s));
    float p = 1.0f + e;
    float d0 = p * lane_swap1(p);
    float r = frcp(d0);
    r = r * __builtin_fmaf(d0, -r, 2.0f);
    r = r * __builtin_fmaf(d0, -r, 2.0f);

    const float4* __restrict__ src = (const float4*)inp + (size_t)row * (TLEN / 2);
    float2* __restrict__ out2 = (float2*)out;

    float* wp = st + r_ * LDPAD + par;    // staging write base (this lane)

    auto step = [&](float va, int t) {
        // input sigmoid: depends only on va -> hoisted ahead of the chain
        float sg  = sigz(__builtin_fmaf(c1i, va, c0i));
        float t1v = __builtin_fmaf(Gn1, x, P1);
        float t2v = __builtin_fmaf(Gn2, x, P2);
        float Av  = __builtin_fmaf(GnA, x, PA);
        float bx  = __builtin_fmaf(sg, Av, x);
        float po  = lane_swap1(p);
        float d   = p * po;
        float nr  = __builtin_fmaf(d, -r, 2.0f);
        r = r * nr;                              // r ~= 1/(p*po), self-correcting
        float m   = p * t2v;
        float Nx  = __builtin_fmaf(po, t1v, m);
        float xn  = __builtin_fmaf(r, Nx, bx);
        float dx  = xn - x;
        x = xn;
        wp[2 * t] = x;                           // ds_write_b32, imm offset
        float w = c1 * dx;
        float h = __builtin_fmaf(T2, w, T1);
        float u = w * h;                         // u = 2^w - 1
        float pn = __builtin_fmaf(e, u, p);
        e = __builtin_fmaf(e, u, e);
        p = pn;
    };

    float4 ba[8], bb[8];
#pragma unroll
    for (int j = 0; j < 8; ++j) ba[j] = src[j];          // chunk 0, half 0

    for (int c = 0; c < NC; ++c) {
#pragma unroll
        for (int j = 0; j < 8; ++j) bb[j] = src[c * 16 + 8 + j];   // half 1
#pragma unroll
        for (int j = 0; j < 8; ++j) {
            float4 f = ba[j];
            step(par ? f.y : f.x, 2 * j);
            step(par ? f.w : f.z, 2 * j + 1);
        }
        if (c + 1 < NC) {
#pragma unroll
            for (int j = 0; j < 8; ++j) ba[j] = src[(c + 1) * 16 + j];
        }
#pragma unroll
        for (int j = 0; j < 8; ++j) {
            float4 f = bb[j];
            step(par ? f.y : f.x, 16 + 2 * j);
            step(par ? f.w : f.z, 16 + 2 * j + 1);
        }
        p = 1.0f + e;   // re-sync invariant (off-chain, once per chunk)

        // flush: 32 rows x 32 steps x (x,y) -> coalesced 256 B runs per row
#pragma unroll
        for (int j = 0; j < 16; ++j) {
            int ro  = 2 * j + (lane >> 5);
            int col = lane & 31;
            float2 v = *(const float2*)&st[ro * LDPAD + col * 2];
            out2[(size_t)(R0 + ro) * TLEN + (size_t)c * K + col] = v;
        }
    }
}

// ---------------------------------------------------------------------------
// Exact fallback (round-1 proven path) for general params.
// ---------------------------------------------------------------------------
struct LaneConst {
    float c1_in, c0_in, c1_sf, c0_sf, c1_ot, c0_ot;
    float gS_in, gS_cr, gS_sf, gP_in, gP_cr, gP_sf;
};

template<bool SHARED>
__device__ __forceinline__ float do_step_exact(float s, float pre_in, const LaneConst& k) {
    float sig_in = sigz(__builtin_fmaf(k.c1_in, pre_in, k.c0_in));
    float sig_sf = sigz(__builtin_fmaf(k.c1_sf, s, k.c0_sf));
    float sig_ot;
    if (SHARED) sig_ot = sig_sf;
    else        sig_ot = sigz(__builtin_fmaf(k.c1_ot, s, k.c0_ot));
    float sig_cr = lane_swap1(sig_ot);
    float S = __builtin_fmaf(k.gS_in, sig_in, __builtin_fmaf(k.gS_cr, sig_cr, k.gS_sf * sig_sf));
    float P = __builtin_fmaf(k.gP_in, sig_in, __builtin_fmaf(k.gP_cr, sig_cr, k.gP_sf * sig_sf));
    return s + __builtin_fmaf(S, -s, P);
}

template<bool SHARED>
__device__ void run_exact(const float* __restrict__ inp, const float* __restrict__ prm,
                          float* __restrict__ out) {
    const int tid = blockIdx.x * 64 + threadIdx.x;
    const int row = tid >> 1;
    const int par = tid & 1;
    const float L2E = 1.4426950408889634f;
    const int inB = par ? 6 : 2, sfB = par ? 22 : 18, otB = par ? 14 : 10, crB = par ? 10 : 14;
    const float invc = 1.0f / prm[par];
    LaneConst k;
    float sd = prm[inB + 2], mn = prm[inB + 1];
    k.c1_in = -sd * L2E; k.c0_in = sd * mn * L2E;
    sd = prm[sfB + 2]; mn = prm[sfB + 1];
    k.c1_sf = -sd * L2E; k.c0_sf = sd * mn * L2E;
    sd = prm[otB + 2]; mn = prm[otB + 1];
    k.c1_ot = -sd * L2E; k.c0_ot = sd * mn * L2E;
    k.gS_in = prm[inB] * invc; k.gP_in = k.gS_in * prm[inB + 3];
    k.gS_sf = prm[sfB] * invc; k.gP_sf = k.gS_sf * prm[sfB + 3];
    k.gS_cr = prm[crB] * invc; k.gP_cr = k.gS_cr * prm[crB + 3];

    const float4* __restrict__ src = (const float4*)inp + (size_t)row * (TLEN / 2);
    float* __restrict__ dst = out + (size_t)row * (TLEN * 2) + par;
    float s = par ? 1.0f : 0.0f;

    float4 cur[UN], nxt[UN];
#pragma unroll
    for (int j = 0; j < UN; ++j) cur[j] = src[j];
    const int NIT = TLEN / (2 * UN);
    for (int it = 0; it < NIT; ++it) {
        if (it + 1 < NIT) {
#pragma unroll
            for (int j = 0; j < UN; ++j) nxt[j] = src[(it + 1) * UN + j];
        }
        float* dptr = dst + it * (UN * 4);
#pragma unroll
        for (int j = 0; j < UN; ++j) {
            float4 f = cur[j];
            s = do_step_exact<SHARED>(s, par ? f.y : f.x, k);
            dptr[j * 4] = s;
            s = do_step_exact<SHARED>(s, par ? f.w : f.z, k);
            dptr[j * 4 + 2] = s;
        }
#pragma unroll
        for (int j = 0; j < UN; ++j) cur[j] = nxt[j];
    }
}

__global__ __launch_bounds__(64, 1)
void memcell_scan(const float* __restrict__ inp, const float* __restrict__ prm,
                  float* __restrict__ out) {
    __shared__ float st[RPB * LDPAD];   // 8.4 KB output staging (wave-synchronous)

    // Device-uniform guard for the fast path:
    //  - shared (mean,std) between self & cross state dirs (xx==xy, yy==yx)
    //  - g >= 0, caps > 0          -> states stay in hull{s0, pots}
    //  - sum(g/cap) <= 0.25        -> no overshoot
    //  - |w| = |c1*dx| <= 0.02     -> deg-2 Taylor of 2^w valid to ~1e-3 over T
    //  - |z| <= 20                 -> e = 2^z no overflow
    const bool shared = (prm[11] == prm[19]) && (prm[12] == prm[20]) &&
                        (prm[15] == prm[23]) && (prm[16] == prm[24]);
    const float capx = prm[0], capy = prm[1];
    const bool gpos = prm[2] >= 0.f && prm[6] >= 0.f && prm[10] >= 0.f &&
                      prm[14] >= 0.f && prm[18] >= 0.f && prm[22] >= 0.f &&
                      capx > 0.f && capy > 0.f;
    const float sx = (prm[2] + prm[14] + prm[18]) / capx;
    const float sy = (prm[6] + prm[10] + prm[22]) / capy;
    const float lox = fminf(0.f, fminf(prm[5], fminf(prm[17], prm[21])));
    const float hix = fmaxf(0.f, fmaxf(prm[5], fmaxf(prm[17], prm[21])));
    const float loy = fminf(1.f, fminf(prm[9], fminf(prm[13], prm[25])));
    const float hiy = fmaxf(1.f, fmaxf(prm[9], fmaxf(prm[13], prm[25])));
    const float L2E = 1.4426950408889634f;
    const float cx = prm[20] * L2E, cy = prm[24] * L2E;
    const float wbx = cx * sx * (hix - lox), wby = cy * sy * (hiy - loy);
    const float zmx = cx * fmaxf(fabsf(lox - prm[19]), fabsf(hix - prm[19]));
    const float zmy = cy * fmaxf(fabsf(loy - prm[23]), fabsf(hiy - prm[23]));
    const bool fast = shared && gpos && sx <= 0.25f && sy <= 0.25f &&
                      wbx <= 0.02f && wby <= 0.02f && zmx <= 20.f && zmy <= 20.f;
    if (fast) {
        run_fast(inp, prm, out, st);
    } else {
        if (shared) run_exact<true >(inp, prm, out);
        else        run_exact<false>(inp, prm, out);
    }
}

extern "C" void kernel_launch(void* const* d_in, const int* in_sizes, int n_in,
                              void* d_out, int out_size, void* d_ws, size_t ws_size,
                              hipStream_t stream) {
    (void)in_sizes; (void)n_in; (void)d_ws; (void)ws_size; (void)out_size;
    const float* inp = (const float*)d_in[0];
    const float* prm = (const float*)d_in[1];
    float* out = (float*)d_out;
    // 128 blocks x 1 wave; 2 lanes per row (x-chain / y-chain).
    memcell_scan<<<dim3(NROWS / RPB), dim3(64), 0, stream>>>(inp, prm, out);
}

// Round 5
// 384.167 us; speedup vs baseline: 1.2731x; 1.2731x over previous
//
#include <hip/hip_runtime.h>

#define TLEN  4096
#define NROWS 4096
#define RPB   32            // rows per wave (= per block)
#define K     32            // timesteps per chunk
#define NC    (TLEN / K)
#define LDPAD 66            // staged-output row pitch (dwords): 64 data + 2 pad
#define UN    8             // exact-path unroll

__device__ __forceinline__ float fexp2(float x) { return __builtin_amdgcn_exp2f(x); }
__device__ __forceinline__ float frcp(float x)  { return __builtin_amdgcn_rcpf(x); }
__device__ __forceinline__ float sigz(float z)  { return frcp(1.0f + fexp2(z)); }

// Swap adjacent lanes (lane ^ 1): DPP quad_perm [1,0,3,2].
__device__ __forceinline__ float lane_swap1(float v) {
    int r = __builtin_amdgcn_update_dpp(0, __float_as_int(v), 0xB1, 0xF, 0xF, true);
    return __int_as_float(r);
}

// Async global->LDS DMA, 16 B per lane. LDS dest = uniform base + lane*16.
// Fire-and-forget: compiler cannot sink it (no VGPR destination).
__device__ __forceinline__ void gload_lds16(const float4* g, float4* l) {
    __builtin_amdgcn_global_load_lds((const __attribute__((address_space(1))) void*)g,
                                     (__attribute__((address_space(3))) void*)l,
                                     16, 0, 0);
}
// Wait all outstanding VMEM (the chunk's 8 DMA loads, kicked ~2000 cyc earlier),
// and pin ordering so following ds_reads can't be hoisted above it.
__device__ __forceinline__ void fence_vm0() {
    __builtin_amdgcn_s_waitcnt(0x0f70);   // vmcnt(0); lgkmcnt/expcnt unconstrained
    __builtin_amdgcn_sched_barrier(0);
}

// ---------------------------------------------------------------------------
// Fast path. Lane pair (2r, 2r+1) owns row r: even lane = x, odd = y.
// Carried state: s (own state), sig = sigmoid(std_self*(s - mean_self)).
// sig updated by deg-2 Taylor in dz = std_self*ds (|dz| <= 0.05 guarded),
// re-synced exactly once per chunk. Cross sigma = partner's sig via DPP.
// Inputs: global_load_lds double-buffer; outputs: LDS-staged coalesced stores.
// ---------------------------------------------------------------------------
__device__ void run_fast(const float* __restrict__ inp, const float* __restrict__ prm,
                         float* __restrict__ out,
                         float4* __restrict__ ibuf,   // [2][16 tp][32 row] float4
                         float* __restrict__ st) {    // [RPB][LDPAD]
    const int lane = threadIdx.x;
    const int R0   = blockIdx.x * RPB;
    const int r_   = lane >> 1;
    const int par  = lane & 1;

    const float L2E = 1.4426950408889634f;
    const int inB = par ? 6 : 2, sfB = par ? 22 : 18, t2B = par ? 10 : 14;
    const float ic  = 1.0f / prm[par];
    const float g1  = prm[sfB] * ic, P1 = g1 * prm[sfB + 3], Gn1 = -g1; // self dir
    const float g2  = prm[t2B] * ic, P2 = g2 * prm[t2B + 3], Gn2 = -g2; // cross dir
    const float gA  = prm[inB] * ic, PA = gA * prm[inB + 3], GnA = -gA; // input dir
    const float c1i = -prm[inB + 2] * L2E, c0i = prm[inB + 2] * prm[inB + 1] * L2E;
    const float sdz = prm[sfB + 2];                       // natural-arg scale
    const float c1s = -sdz * L2E, c0s = sdz * prm[sfB + 1] * L2E;

    float x   = par ? 1.0f : 0.0f;
    float sig = sigz(__builtin_fmaf(c1s, x, c0s));
    float u   = __builtin_fmaf(-sig, sig, sig);           // sig*(1-sig)
    float q   = 0.5f - sig;

    float2* __restrict__ out2 = (float2*)out;
    float*  wp = st + r_ * LDPAD + par;

    // global source: per-lane row = lane&31, half = lane>>5
    const float4* gbase = (const float4*)inp
                        + (size_t)(R0 + (lane & 31)) * (TLEN / 2) + (lane >> 5);
    auto kick = [&](int c) {   // stage chunk c into ibuf[c&1]; layout idx = tp*32+row
        float4* lb = ibuf + ((c & 1) << 9);
        const float4* gp = gbase + c * 16;
#pragma unroll
        for (int j = 0; j < 8; ++j)
            gload_lds16(gp + 2 * j, lb + (j << 6));   // LDS[j*64+lane] <- g
    };

    auto step = [&](float va, int t) {
        float sgin = sigz(__builtin_fmaf(c1i, va, c0i));  // off-chain (va known early)
        float Av  = __builtin_fmaf(GnA, x, PA);
        float t1v = __builtin_fmaf(Gn1, x, P1);
        float t2v = __builtin_fmaf(Gn2, x, P2);
        float m   = sgin * Av;
        float b2  = __builtin_fmaf(sig, t1v, m);
        float sc  = lane_swap1(sig);                      // partner's sigma
        float dx  = __builtin_fmaf(sc, t2v, b2);
        x = x + dx;
        wp[2 * t] = x;                                    // ds_write_b32, imm offset
        float dz  = sdz * dx;
        float tt  = __builtin_fmaf(q, dz, 1.0f);
        float aa  = dz * tt;
        sig = __builtin_fmaf(u, aa, sig);                 // deg-2 Taylor step
        u   = __builtin_fmaf(-sig, sig, sig);
        q   = 0.5f - sig;
    };

    kick(0);
    fence_vm0();
    float4 f0 = ibuf[0 * 32 + r_];
    float4 f1 = ibuf[1 * 32 + r_];
    kick(1);

    for (int c = 0; c < NC; ++c) {
        float4* lb = ibuf + ((c & 1) << 9);
#pragma unroll
        for (int tp = 0; tp < 16; ++tp) {
            float4 f = f0; f0 = f1;
            if (tp < 14) f1 = lb[(tp + 2) * 32 + r_];     // 2-pair lookahead
            step(par ? f.y : f.x, 2 * tp);
            step(par ? f.w : f.z, 2 * tp + 1);
        }
        // exact re-sync: kills Taylor drift (off the per-step chain)
        sig = sigz(__builtin_fmaf(c1s, x, c0s));
        u   = __builtin_fmaf(-sig, sig, sig);
        q   = 0.5f - sig;

        if (c + 1 < NC) {
            fence_vm0();                                  // chunk c+1 DMA complete
            float4* ln = ibuf + (((c + 1) & 1) << 9);
            f0 = ln[0 * 32 + r_];
            f1 = ln[1 * 32 + r_];
        }
        // flush chunk c: 32 rows x 32 steps x (x,y), coalesced 256 B runs
#pragma unroll
        for (int j = 0; j < 16; ++j) {
            int ro  = 2 * j + (lane >> 5);
            int col = lane & 31;
            float2 v = *(const float2*)&st[ro * LDPAD + col * 2];
            out2[(size_t)(R0 + ro) * TLEN + (size_t)c * K + col] = v;
        }
        if (c + 2 < NC) kick(c + 2);                      // reuse just-consumed buffer
    }
}

// ---------------------------------------------------------------------------
// Exact fallback (round-1 proven path) for general params.
// ---------------------------------------------------------------------------
struct LaneConst {
    float c1_in, c0_in, c1_sf, c0_sf, c1_ot, c0_ot;
    float gS_in, gS_cr, gS_sf, gP_in, gP_cr, gP_sf;
};

template<bool SHARED>
__device__ __forceinline__ float do_step_exact(float s, float pre_in, const LaneConst& k) {
    float sig_in = sigz(__builtin_fmaf(k.c1_in, pre_in, k.c0_in));
    float sig_sf = sigz(__builtin_fmaf(k.c1_sf, s, k.c0_sf));
    float sig_ot;
    if (SHARED) sig_ot = sig_sf;
    else        sig_ot = sigz(__builtin_fmaf(k.c1_ot, s, k.c0_ot));
    float sig_cr = lane_swap1(sig_ot);
    float S = __builtin_fmaf(k.gS_in, sig_in, __builtin_fmaf(k.gS_cr, sig_cr, k.gS_sf * sig_sf));
    float P = __builtin_fmaf(k.gP_in, sig_in, __builtin_fmaf(k.gP_cr, sig_cr, k.gP_sf * sig_sf));
    return s + __builtin_fmaf(S, -s, P);
}

template<bool SHARED>
__device__ void run_exact(const float* __restrict__ inp, const float* __restrict__ prm,
                          float* __restrict__ out) {
    const int tid = blockIdx.x * 64 + threadIdx.x;
    const int row = tid >> 1;
    const int par = tid & 1;
    const float L2E = 1.4426950408889634f;
    const int inB = par ? 6 : 2, sfB = par ? 22 : 18, otB = par ? 14 : 10, crB = par ? 10 : 14;
    const float invc = 1.0f / prm[par];
    LaneConst k;
    float sd = prm[inB + 2], mn = prm[inB + 1];
    k.c1_in = -sd * L2E; k.c0_in = sd * mn * L2E;
    sd = prm[sfB + 2]; mn = prm[sfB + 1];
    k.c1_sf = -sd * L2E; k.c0_sf = sd * mn * L2E;
    sd = prm[otB + 2]; mn = prm[otB + 1];
    k.c1_ot = -sd * L2E; k.c0_ot = sd * mn * L2E;
    k.gS_in = prm[inB] * invc; k.gP_in = k.gS_in * prm[inB + 3];
    k.gS_sf = prm[sfB] * invc; k.gP_sf = k.gS_sf * prm[sfB + 3];
    k.gS_cr = prm[crB] * invc; k.gP_cr = k.gS_cr * prm[crB + 3];

    const float4* __restrict__ src = (const float4*)inp + (size_t)row * (TLEN / 2);
    float* __restrict__ dst = out + (size_t)row * (TLEN * 2) + par;
    float s = par ? 1.0f : 0.0f;

    float4 cur[UN], nxt[UN];
#pragma unroll
    for (int j = 0; j < UN; ++j) cur[j] = src[j];
    const int NIT = TLEN / (2 * UN);
    for (int it = 0; it < NIT; ++it) {
        if (it + 1 < NIT) {
#pragma unroll
            for (int j = 0; j < UN; ++j) nxt[j] = src[(it + 1) * UN + j];
        }
        float* dptr = dst + it * (UN * 4);
#pragma unroll
        for (int j = 0; j < UN; ++j) {
            float4 f = cur[j];
            s = do_step_exact<SHARED>(s, par ? f.y : f.x, k);
            dptr[j * 4] = s;
            s = do_step_exact<SHARED>(s, par ? f.w : f.z, k);
            dptr[j * 4 + 2] = s;
        }
#pragma unroll
        for (int j = 0; j < UN; ++j) cur[j] = nxt[j];
    }
}

__global__ __launch_bounds__(64, 1)
void memcell_scan(const float* __restrict__ inp, const float* __restrict__ prm,
                  float* __restrict__ out) {
    __shared__ float4 ibuf[2 * 16 * 32];   // 16 KB input DMA double-buffer
    __shared__ float  st[RPB * LDPAD];     // 8.4 KB output staging

    // Device-uniform guard for the fast path:
    //  - shared (mean,std) between self & cross state dirs (xx==xy, yy==yx)
    //  - g >= 0, caps > 0       -> states stay in hull{s0, pots}
    //  - sum(g/cap) <= 0.25     -> no overshoot
    //  - |dz| = std*|ds| <= 0.05 -> deg-2 sigma-Taylor (+ per-chunk exact resync)
    //  - |z| <= 20              -> sigz well-conditioned
    const bool shared = (prm[11] == prm[19]) && (prm[12] == prm[20]) &&
                        (prm[15] == prm[23]) && (prm[16] == prm[24]);
    const float capx = prm[0], capy = prm[1];
    const bool gpos = prm[2] >= 0.f && prm[6] >= 0.f && prm[10] >= 0.f &&
                      prm[14] >= 0.f && prm[18] >= 0.f && prm[22] >= 0.f &&
                      capx > 0.f && capy > 0.f;
    const float sx = (prm[2] + prm[14] + prm[18]) / capx;
    const float sy = (prm[6] + prm[10] + prm[22]) / capy;
    const float lox = fminf(0.f, fminf(prm[5], fminf(prm[17], prm[21])));
    const float hix = fmaxf(0.f, fmaxf(prm[5], fmaxf(prm[17], prm[21])));
    const float loy = fminf(1.f, fminf(prm[9], fminf(prm[13], prm[25])));
    const float hiy = fmaxf(1.f, fmaxf(prm[9], fmaxf(prm[13], prm[25])));
    const float wbx = prm[20] * sx * (hix - lox), wby = prm[24] * sy * (hiy - loy);
    const float zmx = prm[20] * fmaxf(fabsf(lox - prm[19]), fabsf(hix - prm[19]));
    const float zmy = prm[24] * fmaxf(fabsf(loy - prm[23]), fabsf(hiy - prm[23]));
    const bool fast = shared && gpos && sx <= 0.25f && sy <= 0.25f &&
                      wbx <= 0.05f && wby <= 0.05f && zmx <= 20.f && zmy <= 20.f;
    if (fast) {
        run_fast(inp, prm, out, ibuf, st);
    } else {
        if (shared) run_exact<true >(inp, prm, out);
        else        run_exact<false>(inp, prm, out);
    }
}

extern "C" void kernel_launch(void* const* d_in, const int* in_sizes, int n_in,
                              void* d_out, int out_size, void* d_ws, size_t ws_size,
                              hipStream_t stream) {
    (void)in_sizes; (void)n_in; (void)d_ws; (void)ws_size; (void)out_size;
    const float* inp = (const float*)d_in[0];
    const float* prm = (const float*)d_in[1];
    float* out = (float*)d_out;
    memcell_scan<<<dim3(NROWS / RPB), dim3(64), 0, stream>>>(inp, prm, out);
}